// Round 10
// baseline (118.959 us; speedup 1.0000x reference)
//
#include <hip/hip_runtime.h>
#include <hip/hip_bf16.h>

// KAN harmonic-basis GEMM, v13: BARRIER-FREE wave-private DMA rings.
// out[b,h] = sum_{d,f} basis(x[b,d])[f] * W[d,f,h] + sum_d b[d,h]
//
// f=0 + bias -> fp32 partials c_part[8][256], summed in GEMM epilogue.
// f=1..10    -> bf16 MFMA GEMM, M=16384, N=256, K=2560.
//
// v13 (v8/v11/v12 ledger: wall == SERIAL SUM of pipe busies (VALU 15 +
// MFMA 8 + LDS 13 + L1 8.5 ~= 45us) in every barriered variant. Phase-locked
// homogeneous waves never overlap pipes; occupancy and vmcnt depth didn't
// move it. Fix: remove ALL intra-kernel sync):
//   - Each wave stages its OWN 4 B-chunks/kt (4KB) via global_load_lds into
//     a wave-private 5-slot LDS ring (20KB/wave, 80KB/block, 2 blocks/CU).
//     No s_barrier / __syncthreads in the whole main path. Waves self-pace
//     on their own DMA queue (vmcnt is per-wave), drift into different
//     phases, and overlap VALU/MFMA/LDS/L1 across waves and blocks.
//   - Uniform asm s_waitcnt vmcnt(16) per kt retires exactly stage(kt)
//     (ring depth 5, prefetch dist 4; 16 = 4 stages x 4 loads in flight).
//     x-prefetch loads ride the same queue, are older, retire earlier.
//   - Cost: B-DMA doubles to 2.62MB/CU (wc pair no longer shares) -> L1/LDS
//     pipes ~17us each, but these are overlappable pipe budgets; target
//     wall = max(pipes) ~17-22us, not sum ~45.
//   - Compute/numerics/epilogue = v8's proven (f32 Chebyshev, absmax 0.25).
//   - Ring hazard audit: write slot (kt+4)%5 last read at kt-1, reads
//     lgkm-retired before the DMA issue; clamped tail stages land in
//     never-read slots.

#define BDIM 16384
#define DDIM 256
#define HOUT 256
#define NKT  80
#define BM 64
#define BN 128

typedef __bf16 bf16x8 __attribute__((ext_vector_type(8)));
typedef float floatx4 __attribute__((ext_vector_type(4)));

__device__ __forceinline__ unsigned short f2bf(float f) {
    unsigned int u = __float_as_uint(f);
    return (unsigned short)((u + 0x7FFFu + ((u >> 16) & 1u)) >> 16);
}

__device__ __forceinline__ unsigned int pkbf(float a, float b) {
    __hip_bfloat162 r = __float22bfloat162_rn(make_float2(a, b));
    return *reinterpret_cast<unsigned int*>(&r);
}

// grid 328 x 256 threads.
// blocks [0,320): kt = bid>>2, sub = bid&3:
//   Wfrag[kt][n=t][dd = sub*8 .. +8] = bf16(W[dtile*32+dd][kt%10+1][n])
// blocks [320,328): p = bid-320; c_part[p][h] = sum_{d in p*32..+32} W[d][0][h]+b[d][h]
__global__ void prep_kernel(const float* __restrict__ W, const float* __restrict__ bias,
                            unsigned short* __restrict__ Wfrag, float* __restrict__ c_part) {
    const int bid = blockIdx.x;
    const int t = threadIdx.x;
    if (bid < 4 * NKT) {
        const int kt = bid >> 2;
        const int sub = bid & 3;
        const int dtile = kt / 10;
        const int f = kt - dtile * 10 + 1;
        const int d0 = dtile * 32 + sub * 8;
        const float* wsrc = W + ((size_t)d0 * 11 + f) * 256 + t;
        union { unsigned short s[8]; int4 v; } buf;
#pragma unroll
        for (int dd = 0; dd < 8; ++dd)
            buf.s[dd] = f2bf(wsrc[(size_t)dd * 11 * 256]);
        *(int4*)(Wfrag + ((size_t)kt * 256 + t) * 32 + sub * 8) = buf.v;
    } else {
        const int p = bid - 4 * NKT;
        float acc = 0.f;
#pragma unroll
        for (int dd = 0; dd < 32; ++dd) {
            const int d = p * 32 + dd;
            acc += W[(size_t)(d * 11) * 256 + t] + bias[(size_t)d * 256 + t];
        }
        c_part[p * 256 + t] = acc;
    }
}

__global__ __launch_bounds__(256, 2)
void kan_gemm(const float* __restrict__ x, const unsigned short* __restrict__ Wfrag,
              const float* __restrict__ c_part, float* __restrict__ out) {
    // wave-private rings: [wave][slot][chunk j*512 + lane*8 shorts] = 81,920 B
    __shared__ unsigned short Bs[4][5][2048];

    const int t = threadIdx.x;
    const int m0 = blockIdx.x * BM;
    const int h0 = blockIdx.y * BN;

    const int lane = t & 63;
    const int wave = t >> 6;         // 0..3
    const int wr = wave >> 1;        // row half (32 rows)
    const int wc = wave & 1;         // col half (64 cols)
    const int l15 = lane & 15;
    const int koff = lane >> 4;

    floatx4 acc[2][4];
#pragma unroll
    for (int i = 0; i < 2; ++i)
#pragma unroll
        for (int j = 0; j < 4; ++j)
            acc[i][j] = (floatx4){0.f, 0.f, 0.f, 0.f};

    // lane's x rows: i=0 -> m0 + wr*32 + l15, i=1 -> +16; d-slots koff*8..+8
    const float* xr0 = x + (size_t)(m0 + wr * 32 + l15) * DDIM + koff * 8;

    // per-lane global B base for this wave's 4 chunks (cols h0+wc*64+j*16+l15,
    // dgroup koff). chunk j at +j*512 shorts; kt at +kt*8192 shorts.
    const unsigned short* bb = Wfrag + (size_t)(h0 + wc * 64 + l15) * 32 + koff * 8;
    unsigned short* ring = &Bs[wave][0][0];

    // ---- prologue: x for dtile 0, then stage kt=0..3 into slots 0..3 ----
    float4 xn[4];
    xn[0] = *(const float4*)(xr0 + 0);
    xn[1] = *(const float4*)(xr0 + 4);
    xn[2] = *(const float4*)(xr0 + 16 * DDIM + 0);
    xn[3] = *(const float4*)(xr0 + 16 * DDIM + 4);

#pragma unroll
    for (int p = 0; p < 4; ++p)
#pragma unroll
        for (int j = 0; j < 4; ++j)
            __builtin_amdgcn_global_load_lds((const void*)(bb + (size_t)p * 8192 + j * 512),
                                             (void*)(ring + p * 2048 + j * 512), 16, 0, 0);

    // Chebyshev state (f32, v8-proven numerics)
    float sc[16], cc[16], sp[16], cp[16], t2c[16];

#pragma unroll 1
    for (int dt = 0; dt < 8; ++dt) {
        // ---- dtile start: sincos of 16 elems (x from regs) ----
        {
            const float xv[16] = {xn[0].x, xn[0].y, xn[0].z, xn[0].w,
                                  xn[1].x, xn[1].y, xn[1].z, xn[1].w,
                                  xn[2].x, xn[2].y, xn[2].z, xn[2].w,
                                  xn[3].x, xn[3].y, xn[3].z, xn[3].w};
#pragma unroll
            for (int g = 0; g < 16; ++g) {
                __sincosf(xv[g], &sc[g], &cc[g]);
                t2c[g] = cc[g] + cc[g];
                sp[g] = 0.f;
                cp[g] = 1.f;
            }
        }

#pragma unroll
        for (int k5 = 0; k5 < 10; ++k5) {
            // slot for this kt: (dt*10+k5)%5 == k5%5 (compile-time)
            const int slot = k5 % 5;
            const int wslot = (k5 + 4) % 5;

            // ---- issue stage(kt+4) into wslot (clamped redundant tail) ----
            {
                int kt2 = dt * 10 + k5 + 4;
                if (kt2 > 79) kt2 = 79;
#pragma unroll
                for (int j = 0; j < 4; ++j)
                    __builtin_amdgcn_global_load_lds(
                        (const void*)(bb + (size_t)kt2 * 8192 + j * 512),
                        (void*)(ring + wslot * 2048 + j * 512), 16, 0, 0);
            }

            // x prefetch for next dtile, mid-dtile (rides the vmcnt queue,
            // older than the stages waited on at the next dtile)
            if (k5 == 5 && dt < 7) {
                xn[0] = *(const float4*)(xr0 + (dt + 1) * 32 + 0);
                xn[1] = *(const float4*)(xr0 + (dt + 1) * 32 + 4);
                xn[2] = *(const float4*)(xr0 + 16 * DDIM + (dt + 1) * 32 + 0);
                xn[3] = *(const float4*)(xr0 + 16 * DDIM + (dt + 1) * 32 + 4);
            }

            // ---- per-wave counted wait: retires exactly stage(kt) ----
            asm volatile("s_waitcnt vmcnt(16)" ::: "memory");
            __builtin_amdgcn_sched_barrier(0);

            // ---- pack A, read B from own ring, 8 MFMA ----
            const float* src = (k5 & 1) ? cc : sc;   // even: sin(kx), odd: cos(kx)
            union { unsigned int u[4]; bf16x8 v; } a0, a1;
#pragma unroll
            for (int p = 0; p < 4; ++p) {
                a0.u[p] = pkbf(src[2 * p], src[2 * p + 1]);
                a1.u[p] = pkbf(src[8 + 2 * p], src[8 + 2 * p + 1]);
            }

            const unsigned short* fb = ring + slot * 2048 + lane * 8;
            const bf16x8 b0 = *(const bf16x8*)(fb);
            const bf16x8 b1 = *(const bf16x8*)(fb + 512);
            const bf16x8 b2 = *(const bf16x8*)(fb + 1024);
            const bf16x8 b3 = *(const bf16x8*)(fb + 1536);

            acc[0][0] = __builtin_amdgcn_mfma_f32_16x16x32_bf16(a0.v, b0, acc[0][0], 0, 0, 0);
            acc[1][0] = __builtin_amdgcn_mfma_f32_16x16x32_bf16(a1.v, b0, acc[1][0], 0, 0, 0);
            acc[0][1] = __builtin_amdgcn_mfma_f32_16x16x32_bf16(a0.v, b1, acc[0][1], 0, 0, 0);
            acc[1][1] = __builtin_amdgcn_mfma_f32_16x16x32_bf16(a1.v, b1, acc[1][1], 0, 0, 0);
            acc[0][2] = __builtin_amdgcn_mfma_f32_16x16x32_bf16(a0.v, b2, acc[0][2], 0, 0, 0);
            acc[1][2] = __builtin_amdgcn_mfma_f32_16x16x32_bf16(a1.v, b2, acc[1][2], 0, 0, 0);
            acc[0][3] = __builtin_amdgcn_mfma_f32_16x16x32_bf16(a0.v, b3, acc[0][3], 0, 0, 0);
            acc[1][3] = __builtin_amdgcn_mfma_f32_16x16x32_bf16(a1.v, b3, acc[1][3], 0, 0, 0);

            // advance harmonic after each cos emit (except the last)
            if ((k5 & 1) && k5 < 9) {
#pragma unroll
                for (int g = 0; g < 16; ++g) {
                    const float ns = t2c[g] * sc[g] - sp[g];
                    const float nc = t2c[g] * cc[g] - cp[g];
                    sp[g] = sc[g]; cp[g] = cc[g];
                    sc[g] = ns;   cc[g] = nc;
                }
            }
        }
    }

    // drain redundant tail DMAs
    asm volatile("s_waitcnt vmcnt(0)" ::: "memory");

    // ---- epilogue: C/D layout col=lane&15, row=(lane>>4)*4+reg ----
    float cj[4];
#pragma unroll
    for (int j = 0; j < 4; ++j) {
        const int col = h0 + wc * 64 + j * 16 + l15;
        float s = 0.f;
#pragma unroll
        for (int q = 0; q < 8; ++q) s += c_part[q * 256 + col];
        cj[j] = s;
    }
#pragma unroll
    for (int i = 0; i < 2; ++i) {
        const int row0 = m0 + wr * 32 + i * 16 + koff * 4;
#pragma unroll
        for (int j = 0; j < 4; ++j) {
            const int col = h0 + wc * 64 + j * 16 + l15;
#pragma unroll
            for (int r = 0; r < 4; ++r)
                out[(size_t)(row0 + r) * HOUT + col] = acc[i][j][r] + cj[j];
        }
    }
}

extern "C" void kernel_launch(void* const* d_in, const int* in_sizes, int n_in,
                              void* d_out, int out_size, void* d_ws, size_t ws_size,
                              hipStream_t stream) {
    const float* x = (const float*)d_in[0];
    const float* W = (const float*)d_in[1];
    const float* b = (const float*)d_in[2];
    float* out = (float*)d_out;

    unsigned short* Wfrag = (unsigned short*)d_ws;                      // 1,310,720 B
    float* c_part = (float*)((char*)d_ws + (size_t)NKT * 256 * 32 * 2); // 8 KB

    prep_kernel<<<4 * NKT + 8, 256, 0, stream>>>(W, b, Wfrag, c_part);
    kan_gemm<<<dim3(BDIM / BM, HOUT / BN), 256, 0, stream>>>(x, Wfrag, c_part, out);
}

// Round 11
// 102.410 us; speedup vs baseline: 1.1616x; 1.1616x over previous
//
#include <hip/hip_runtime.h>
#include <hip/hip_bf16.h>

// KAN harmonic-basis GEMM, v14: BM=128 to HALVE the global_load_lds DMA term.
// out[b,h] = sum_{d,f} basis(x[b,d])[f] * W[d,f,h] + sum_d b[d,h]
//
// f=0 + bias -> fp32 partials c_part[8][256], summed in GEMM epilogue.
// f=1..10    -> bf16 MFMA GEMM, M=16384, N=256, K=2560.
//
// v14 (v13 post-mortem: barrier-free private rings = +11us for +1.31MB/CU of
// DMA -> measured DMA path ~30 B/cyc/CU -> v12's 1.31MB/CU costs ~18us, the
// LARGEST term of the 45us wall. v11/v12/v13 failed because none shrank a
// term):
//   - BM=128 x BN=128, grid 128x2 = 256 blocks = 1 block/CU (forced by 96KB
//     LDS pad). 8 waves = wr(4) x wc(2); per-wave stream IDENTICAL to v12
//     (32r x 64c x 80kt, 8 MFMA/kt). Block stages 655KB instead of 2 blocks
//     staging 1.31MB -> DMA/CU and LDS-DMA-writes HALVE; LDS reads, VALU,
//     MFMA, occupancy (2 w/SIMD) conserved.
//   - v12's counted-vmcnt phase structure, 8-wave: 5-slot ring (slot=q, since
//     5 phases/dtile == ring depth), 2 loads/wave/phase, prologue stages
//     s(0..2) + x(dt0).
//   - vmcnt audit (ages oldest->newest). Steady q∉{2,3}: enter {s(p),s(p+1),
//     s(p+2)}=6, +s(p+3)=8, vmcnt(6) retires s(p) -> compute p safe. q==2:
//     +x4 +s(p+3)=12, vmcnt(10) retires s(p) only. q==3: 12 in flight,
//     vmcnt(10) retires s(p+1). q==4: vmcnt(6) retires s(p+2)+x4 -> x done
//     before next q0's sincos. WAR: s(p+3) overwrites slot read at p-2,
//     all waves passed the p-1 barrier after that read.
//   - One s_barrier per phase (publishes all 16 chunks); numerics = v8/v12
//     (f32 sincos + Chebyshev, absmax 0.25).

#define BDIM 16384
#define DDIM 256
#define HOUT 256
#define NKT  80
#define BM 128
#define BN 128

typedef __bf16 bf16x8 __attribute__((ext_vector_type(8)));
typedef float floatx4 __attribute__((ext_vector_type(4)));

__device__ __forceinline__ unsigned short f2bf(float f) {
    unsigned int u = __float_as_uint(f);
    return (unsigned short)((u + 0x7FFFu + ((u >> 16) & 1u)) >> 16);
}

__device__ __forceinline__ unsigned int pkbf(float a, float b) {
    __hip_bfloat162 r = __float22bfloat162_rn(make_float2(a, b));
    return *reinterpret_cast<unsigned int*>(&r);
}

// grid 328 x 256 threads.
// blocks [0,320): kt = bid>>2, sub = bid&3:
//   Wfrag[kt][n=t][dd = sub*8 .. +8] = bf16(W[dtile*32+dd][kt%10+1][n])
// blocks [320,328): p = bid-320; c_part[p][h] = sum_{d in p*32..+32} W[d][0][h]+b[d][h]
__global__ void prep_kernel(const float* __restrict__ W, const float* __restrict__ bias,
                            unsigned short* __restrict__ Wfrag, float* __restrict__ c_part) {
    const int bid = blockIdx.x;
    const int t = threadIdx.x;
    if (bid < 4 * NKT) {
        const int kt = bid >> 2;
        const int sub = bid & 3;
        const int dtile = kt / 10;
        const int f = kt - dtile * 10 + 1;
        const int d0 = dtile * 32 + sub * 8;
        const float* wsrc = W + ((size_t)d0 * 11 + f) * 256 + t;
        union { unsigned short s[8]; int4 v; } buf;
#pragma unroll
        for (int dd = 0; dd < 8; ++dd)
            buf.s[dd] = f2bf(wsrc[(size_t)dd * 11 * 256]);
        *(int4*)(Wfrag + ((size_t)kt * 256 + t) * 32 + sub * 8) = buf.v;
    } else {
        const int p = bid - 4 * NKT;
        float acc = 0.f;
#pragma unroll
        for (int dd = 0; dd < 32; ++dd) {
            const int d = p * 32 + dd;
            acc += W[(size_t)(d * 11) * 256 + t] + bias[(size_t)d * 256 + t];
        }
        c_part[p * 256 + t] = acc;
    }
}

__global__ __launch_bounds__(512, 2)
void kan_gemm(const float* __restrict__ x, const unsigned short* __restrict__ Wfrag,
              const float* __restrict__ c_part, float* __restrict__ out) {
    // 5-slot ring of 16KB phases; 6th slot = pad to 96KB -> 1 block/CU forced.
    __shared__ unsigned short Bs[6][2 * 8 * 512];

    const int t = threadIdx.x;
    const int m0 = blockIdx.x * BM;
    const int h0 = blockIdx.y * BN;

    const int lane = t & 63;
    const int wave = t >> 6;         // 0..7
    const int wr = wave >> 1;        // row quarter (32 rows)
    const int wc = wave & 1;         // col half (64 cols)
    const int l15 = lane & 15;
    const int koff = lane >> 4;

    floatx4 acc[2][4];
#pragma unroll
    for (int i = 0; i < 2; ++i)
#pragma unroll
        for (int j = 0; j < 4; ++j)
            acc[i][j] = (floatx4){0.f, 0.f, 0.f, 0.f};

    // lane's x rows: i=0 -> m0 + wr*32 + l15, i=1 -> +16; d-slots koff*8..+8
    const float* xr0 = x + (size_t)(m0 + wr * 32 + l15) * DDIM + koff * 8;

    // per-lane global base: this wave's 2 chunks per phase.
    // chunk c in [0,16): ktl = c>>3, f = c&7; wave w owns c = {2w, 2w+1}.
    const unsigned short* bb = Wfrag + (size_t)(h0 + l15 * 1) * 0 + 0; // (unused helper, kept simple below)

    // ---- prologue: x for dtile 0, then stage phases 0,1,2 (6 loads/wave) ----
    float4 xn[4];
    xn[0] = *(const float4*)(xr0 + 0);
    xn[1] = *(const float4*)(xr0 + 4);
    xn[2] = *(const float4*)(xr0 + 16 * DDIM + 0);
    xn[3] = *(const float4*)(xr0 + 16 * DDIM + 4);

#pragma unroll
    for (int p = 0; p < 3; ++p) {
#pragma unroll
        for (int s = 0; s < 2; ++s) {
            const int c = wave * 2 + s;
            const int ktl = c >> 3;
            const int f = c & 7;
            const unsigned short* g = Wfrag + (size_t)(p * 2 + ktl) * 8192
                                    + (h0 + f * 16 + l15) * 32 + koff * 8;
            __builtin_amdgcn_global_load_lds((const void*)g,
                (void*)(&Bs[p][0] + c * 512), 16, 0, 0);
        }
    }

    // Chebyshev state (f32, v8-proven numerics)
    float sc[16], cc[16], sp[16], cp[16], t2c[16];

#pragma unroll 1
    for (int dt = 0; dt < 8; ++dt) {
#pragma unroll
        for (int q = 0; q < 5; ++q) {
            // phase p = dt*5 + q; compute slot = q; write slot = (q+3)%5.

            // x prefetch for next dtile at q==2 (before stage issue; rides
            // the queue, fully retired by q==4's vmcnt(6)). dt==7: redundant
            // reload of dt7's x keeps counts uniform.
            if (q == 2) {
                const int dn = (dt < 7) ? dt + 1 : 7;
                xn[0] = *(const float4*)(xr0 + dn * 32 + 0);
                xn[1] = *(const float4*)(xr0 + dn * 32 + 4);
                xn[2] = *(const float4*)(xr0 + 16 * DDIM + dn * 32 + 0);
                xn[3] = *(const float4*)(xr0 + 16 * DDIM + dn * 32 + 4);
            }

            // ---- issue stage(p+3) into slot (q+3)%5 (clamped tail) ----
            {
                int pt = dt * 5 + q + 3;
                if (pt > 39) pt = 39;
#pragma unroll
                for (int s = 0; s < 2; ++s) {
                    const int c = wave * 2 + s;
                    const int ktl = c >> 3;
                    const int f = c & 7;
                    const unsigned short* g = Wfrag + (size_t)(pt * 2 + ktl) * 8192
                                            + (h0 + f * 16 + l15) * 32 + koff * 8;
                    __builtin_amdgcn_global_load_lds((const void*)g,
                        (void*)(&Bs[(q + 3) % 5][0] + c * 512), 16, 0, 0);
                }
            }

            // ---- counted wait (audited) + publish barrier ----
            __builtin_amdgcn_sched_barrier(0);
            if (q == 2 || q == 3) {
                asm volatile("s_waitcnt vmcnt(10)" ::: "memory");
            } else {
                asm volatile("s_waitcnt vmcnt(6)" ::: "memory");
            }
            __builtin_amdgcn_s_barrier();
            __builtin_amdgcn_sched_barrier(0);

            if (q == 0) {
                // ---- dtile start: sincos of 16 elems; Chebyshev init ----
                const float xv[16] = {xn[0].x, xn[0].y, xn[0].z, xn[0].w,
                                      xn[1].x, xn[1].y, xn[1].z, xn[1].w,
                                      xn[2].x, xn[2].y, xn[2].z, xn[2].w,
                                      xn[3].x, xn[3].y, xn[3].z, xn[3].w};
#pragma unroll
                for (int g = 0; g < 16; ++g) {
                    __sincosf(xv[g], &sc[g], &cc[g]);
                    t2c[g] = cc[g] + cc[g];
                    sp[g] = 0.f;
                    cp[g] = 1.f;
                }
            }

            // ---- compute 2 kt (harmonic k = q+1: sin then cos) ----
#pragma unroll
            for (int s = 0; s < 2; ++s) {
                const float* src = s ? cc : sc;

                union { unsigned int u[4]; bf16x8 v; } a0, a1;
#pragma unroll
                for (int p = 0; p < 4; ++p) {
                    a0.u[p] = pkbf(src[2 * p], src[2 * p + 1]);
                    a1.u[p] = pkbf(src[8 + 2 * p], src[8 + 2 * p + 1]);
                }

                const unsigned short* fb = &Bs[q][(s * 8 + wc * 4) * 512 + lane * 8];
                const bf16x8 b0 = *(const bf16x8*)(fb);
                const bf16x8 b1 = *(const bf16x8*)(fb + 512);
                const bf16x8 b2 = *(const bf16x8*)(fb + 1024);
                const bf16x8 b3 = *(const bf16x8*)(fb + 1536);

                acc[0][0] = __builtin_amdgcn_mfma_f32_16x16x32_bf16(a0.v, b0, acc[0][0], 0, 0, 0);
                acc[1][0] = __builtin_amdgcn_mfma_f32_16x16x32_bf16(a1.v, b0, acc[1][0], 0, 0, 0);
                acc[0][1] = __builtin_amdgcn_mfma_f32_16x16x32_bf16(a0.v, b1, acc[0][1], 0, 0, 0);
                acc[1][1] = __builtin_amdgcn_mfma_f32_16x16x32_bf16(a1.v, b1, acc[1][1], 0, 0, 0);
                acc[0][2] = __builtin_amdgcn_mfma_f32_16x16x32_bf16(a0.v, b2, acc[0][2], 0, 0, 0);
                acc[1][2] = __builtin_amdgcn_mfma_f32_16x16x32_bf16(a1.v, b2, acc[1][2], 0, 0, 0);
                acc[0][3] = __builtin_amdgcn_mfma_f32_16x16x32_bf16(a0.v, b3, acc[0][3], 0, 0, 0);
                acc[1][3] = __builtin_amdgcn_mfma_f32_16x16x32_bf16(a1.v, b3, acc[1][3], 0, 0, 0);

                // advance harmonic after the cos emit (except k=5)
                if (s == 1 && q < 4) {
#pragma unroll
                    for (int g = 0; g < 16; ++g) {
                        const float ns = t2c[g] * sc[g] - sp[g];
                        const float nc = t2c[g] * cc[g] - cp[g];
                        sp[g] = sc[g]; cp[g] = cc[g];
                        sc[g] = ns;   cc[g] = nc;
                    }
                }
            }
        }
    }

    // drain redundant tail DMAs
    asm volatile("s_waitcnt vmcnt(0)" ::: "memory");

    // ---- epilogue: C/D layout col=lane&15, row=(lane>>4)*4+reg ----
    float cj[4];
#pragma unroll
    for (int j = 0; j < 4; ++j) {
        const int col = h0 + wc * 64 + j * 16 + l15;
        float s = 0.f;
#pragma unroll
        for (int q = 0; q < 8; ++q) s += c_part[q * 256 + col];
        cj[j] = s;
    }
#pragma unroll
    for (int i = 0; i < 2; ++i) {
        const int row0 = m0 + wr * 32 + i * 16 + koff * 4;
#pragma unroll
        for (int j = 0; j < 4; ++j) {
            const int col = h0 + wc * 64 + j * 16 + l15;
#pragma unroll
            for (int r = 0; r < 4; ++r)
                out[(size_t)(row0 + r) * HOUT + col] = acc[i][j][r] + cj[j];
        }
    }
}

extern "C" void kernel_launch(void* const* d_in, const int* in_sizes, int n_in,
                              void* d_out, int out_size, void* d_ws, size_t ws_size,
                              hipStream_t stream) {
    const float* x = (const float*)d_in[0];
    const float* W = (const float*)d_in[1];
    const float* b = (const float*)d_in[2];
    float* out = (float*)d_out;

    unsigned short* Wfrag = (unsigned short*)d_ws;                      // 1,310,720 B
    float* c_part = (float*)((char*)d_ws + (size_t)NKT * 256 * 32 * 2); // 8 KB

    prep_kernel<<<4 * NKT + 8, 256, 0, stream>>>(W, b, Wfrag, c_part);
    kan_gemm<<<dim3(BDIM / BM, HOUT / BN), 512, 0, stream>>>(x, Wfrag, c_part, out);
}